// Round 4
// baseline (88.963 us; speedup 1.0000x reference)
//
#include <hip/hip_runtime.h>
#include <stdint.h>

// ---------------------------------------------------------------------------
// quantized_conv: bit-serial IMC conv simulation, exact integer path via i8 MFMA
//
// out[b,o,p] = (norm/255) * sum_{c,s,t} 4^(s+t) *
//    ( min(31, sum_f a_s[f]*wp_t[f]) - min(31, sum_f a_s[f]*wn_t[f]) )
// Exact in i32 -> bit-exact vs fp32 ref (R1-R3: absmax=0).
//
// R4: fix R3's latency-bound 1-wave/SIMD regime (Occ 10.5%, all pipes idle).
// Stream dim s split across waves: block = 32m x 16o, 8 waves = (msub 2)x(s 4),
// grid 512 = 2 blocks/CU, 16 waves/CU. Per-wave partials carry 4^(s+t); final
// cross-s sum via LDS reduce (integers < 2^24, exact). Still d_ws-free (R3
// showed ws-using rounds pay ~40us of poison-fill in the timed window).
// ---------------------------------------------------------------------------

typedef int v4i __attribute__((ext_vector_type(4)));
typedef unsigned int v4u __attribute__((ext_vector_type(4)));

#define BROW  656   // LDS row stride bytes (164 dwords)
#define BROWD 164

// extract 2-bit field s of each byte in a packed dword vector
__device__ __forceinline__ v4i bits2(v4u w, int s) {
  v4u r = (w >> (unsigned)(2 * s)) & 0x03030303u;
  return (v4i)r;
}

__global__ __launch_bounds__(512, 4) void k_fused(
    const float* __restrict__ in, const float* __restrict__ w,
    float* __restrict__ out)
{
  __shared__ __align__(16) unsigned char Al[32 * BROW];  // patches [m_l][kpos]; reused as reduce buf
  __shared__ __align__(16) unsigned char Bl[32 * BROW];  // weights [sign*16+o_l][kpos]
  __shared__ float s_part[8];

  int tid = threadIdx.x;
  int bid = blockIdx.x;
  if (bid == 0 && tid == 0) out[262144] = 0.0f;   // second tuple output

  int mtile = bid >> 2;        // 0..127: 32 consecutive patches = one y row of one image
  int otile = bid & 3;         // o base = otile*16

  // ---- phase A: global weight |max| (redundant per block; weights L2-resident) ----
  float amax = 0.0f;
  {
    const float4* w4 = (const float4*)w;
    #pragma unroll 6
    for (int i = 0; i < 18; ++i) {                // 9216 float4 / 512 thr
      float4 v = w4[i * 512 + tid];
      amax = fmaxf(amax, fmaxf(fmaxf(fabsf(v.x), fabsf(v.y)),
                               fmaxf(fabsf(v.z), fabsf(v.w))));
    }
  }

  // ---- phase B: zero the chunk-pad dwords of Bl (512 dwords, 1/thread) ----
  {
    int row  = tid >> 4;                          // sign*16 + o_l
    int slot = tid & 15;
    int c, dw;
    if (slot < 12) { c = (slot * 11) >> 5; dw = 29 + slot - c * 3; }  // c<4: dw 29..31
    else           { c = 4;                dw = slot + 16; }          // c=4: dw 28..31
    ((unsigned int*)Bl)[row * BROWD + c * 32 + dw] = 0u;
  }

  // ---- phase C: unfold + quantize 32 patches into Al ----
  {
    int b = mtile >> 5;
    int yrow = mtile & 31;
    #pragma unroll 2
    for (int i = 0; i < 10; ++i) {
      int d = i * 512 + tid;                             // [0,5120) dwords
      unsigned int m_l = ((unsigned)d * 52429u) >> 23;   // d/160
      int kw = d - (int)m_l * 160;
      unsigned int pack = 0;
      #pragma unroll
      for (int q = 0; q < 4; ++q) {
        int k = kw * 4 + q;
        int c = k >> 7, j = k & 127;
        int csize = (c == 4) ? 112 : 116;
        unsigned int bv = 0;
        if (j < csize) {
          unsigned int f  = c * 116 + j;          // f = ic*9 + dy*3 + dx
          unsigned int ic = (f * 7282u) >> 16;    // f/9
          unsigned int r9 = f - ic * 9u;
          unsigned int dy = (r9 * 11u) >> 5;      // r9/3
          unsigned int dx = r9 - dy * 3u;
          int iy = yrow + (int)dy - 1, ix = (int)m_l + (int)dx - 1;
          if (iy >= 0 && iy < 32 && ix >= 0 && ix < 32) {
            float xv = in[((b * 64 + (int)ic) * 32 + iy) * 32 + ix];
            xv = fminf(fmaxf(xv, -8.0f), 7.9375f);          // fixed-point clip
            bv = (unsigned int)((int)rintf(xv * 16.0f) & 255);  // 2's-compl byte
          }
        }
        pack |= bv << (8 * q);
      }
      ((unsigned int*)Al)[m_l * BROWD + kw] = pack;
    }
  }

  // ---- finish |max|: wave reduce, share via LDS ----
  #pragma unroll
  for (int off = 32; off > 0; off >>= 1)
    amax = fmaxf(amax, __shfl_down(amax, off, 64));
  if ((tid & 63) == 0) s_part[tid >> 6] = amax;
  __syncthreads();

  float norm = s_part[0];
  #pragma unroll
  for (int i = 1; i < 8; ++i) norm = fmaxf(norm, s_part[i]);
  if (!(norm > 0.0f)) norm = 1.0f;
  float sc = 255.0f / norm;

  // ---- phase D: quantize this otile's 16o x 576f weights into Bl ----
  #pragma unroll
  for (int i = 0; i < 5; ++i) {
    int idx = i * 512 + tid;                              // [0,2304) float4 groups
    if (idx < 2304) {
      unsigned int o_l = ((unsigned)idx * 1821u) >> 18;   // idx/144
      int g = idx - (int)o_l * 144;
      int c, jg;
      if (g < 116) { c = (g * 565) >> 14; jg = (g - c * 29) * 4; }  // c=g/29
      else         { c = 4;               jg = (g - 116) * 4; }
      int f = c * 116 + jg;
      float4 wv = *(const float4*)(w + (otile * 16 + (int)o_l) * 576 + f);
      float vv[4] = {wv.x, wv.y, wv.z, wv.w};
      unsigned int pd = 0, nd = 0;
      #pragma unroll
      for (int q = 0; q < 4; ++q) {
        unsigned int pb = (unsigned int)(int)rintf(fmaxf(vv[q], 0.0f) * sc);
        unsigned int nb = (unsigned int)(int)rintf(fmaxf(-vv[q], 0.0f) * sc);
        pd |= pb << (8 * q);
        nd |= nb << (8 * q);
      }
      int dwo = c * 32 + (jg >> 2);
      ((unsigned int*)Bl)[(int)o_l * BROWD + dwo]        = pd;   // pos
      ((unsigned int*)Bl)[(16 + (int)o_l) * BROWD + dwo] = nd;   // neg
    }
  }
  __syncthreads();

  // ---- phase E: MFMA; wave = msub*4 + s (weights = A-operand -> D[o][m]) ----
  int lane = tid & 63, wave = tid >> 6;
  int s = wave & 3, msub = wave >> 2;
  int r16 = lane & 15, kgrp = lane >> 4;

  const unsigned char* ap = Al + (msub * 16 + r16) * BROW + kgrp * 16;
  const unsigned char* bp = Bl + r16 * BROW + kgrp * 16;
  const unsigned char* bn = Bl + (16 + r16) * BROW + kgrp * 16;

  v4i outacc = {0, 0, 0, 0};

  #pragma unroll
  for (int c = 0; c < 5; ++c) {
    v4u a0 = *(const v4u*)(ap + c * 128);
    v4u a1 = *(const v4u*)(ap + c * 128 + 64);
    v4u p0 = *(const v4u*)(bp + c * 128);
    v4u p1 = *(const v4u*)(bp + c * 128 + 64);
    v4u n0 = *(const v4u*)(bn + c * 128);
    v4u n1 = *(const v4u*)(bn + c * 128 + 64);

    v4i as0 = bits2(a0, s), as1 = bits2(a1, s);   // this wave's stream digits

    #pragma unroll
    for (int t = 0; t < 4; ++t) {
      v4i z = {0, 0, 0, 0};
      v4i pacc = __builtin_amdgcn_mfma_i32_16x16x64_i8(bits2(p0, t), as0, z, 0, 0, 0);
      pacc     = __builtin_amdgcn_mfma_i32_16x16x64_i8(bits2(p1, t), as1, pacc, 0, 0, 0);
      v4i nacc = __builtin_amdgcn_mfma_i32_16x16x64_i8(bits2(n0, t), as0, z, 0, 0, 0);
      nacc     = __builtin_amdgcn_mfma_i32_16x16x64_i8(bits2(n1, t), as1, nacc, 0, 0, 0);
      int sh = 2 * (s + t);
      #pragma unroll
      for (int r = 0; r < 4; ++r) {
        // ADC: nonneg int sums; clip(round(x),0,31) == min(x,31)
        int dd = (pacc[r] < 31 ? pacc[r] : 31) - (nacc[r] < 31 ? nacc[r] : 31);
        outacc[r] += dd << sh;    // per-s partial <= 843200, total <= 1.12e6, exact
      }
    }
  }

  // ---- epilogue: cross-s reduce via LDS (reuse Al), waves s==0 store ----
  __syncthreads();                      // all Al/Bl reads done
  v4i* red = (v4i*)Al;
  red[wave * 64 + lane] = outacc;
  __syncthreads();

  if (s == 0) {
    v4i acc = red[(msub * 4 + 0) * 64 + lane];
    #pragma unroll
    for (int ss = 1; ss < 4; ++ss)
      acc += red[(msub * 4 + ss) * 64 + lane];
    float fsc = norm / 255.0f;
    int pg = mtile * 32 + msub * 16 + r16;       // global patch index
    int b = pg >> 10, p = pg & 1023;
    int oc = otile * 16 + kgrp * 4;
    #pragma unroll
    for (int r = 0; r < 4; ++r)                  // D: row(o)=kgrp*4+r, col(m)=r16
      out[(b * 64 + oc + r) * 1024 + p] = (float)acc[r] * fsc;
  }
}

extern "C" void kernel_launch(void* const* d_in, const int* in_sizes, int n_in,
                              void* d_out, int out_size, void* d_ws, size_t ws_size,
                              hipStream_t stream) {
  const float* inp = (const float*)d_in[0];   // (4,64,32,32) f32
  const float* wgt = (const float*)d_in[1];   // (64,64,3,3)  f32
  float* out = (float*)d_out;                 // 262144 + 1 f32
  (void)d_ws; (void)ws_size;
  k_fused<<<512, 512, 0, stream>>>(inp, wgt, out);
}

// Round 5
// 82.852 us; speedup vs baseline: 1.0737x; 1.0737x over previous
//
#include <hip/hip_runtime.h>
#include <stdint.h>

// ---------------------------------------------------------------------------
// quantized_conv: bit-serial IMC conv simulation, exact integer path via i8 MFMA
//
// out[b,o,p] = (norm/255) * sum_{c,s,t} 4^(s+t) *
//    ( min(31, sum_f a_s[f]*wp_t[f]) - min(31, sum_f a_s[f]*wn_t[f]) )
// Exact in i32 -> bit-exact vs fp32 ref (R1-R4: absmax=0).
//
// R5: A/B the harness-floor hypothesis. R2's ws-staged 2-kernel graph timed
// 79.6us; R3/R4's ws-free 1-kernel graphs timed ~89us despite faster kernels
// (top dispatch = 256MiB d_ws poison fill in all rounds). This round: R2's
// graph structure (k_prep stages Aq+max partials in d_ws -> k_main) with R4's
// occupancy fix in k_main (stream dim s split across waves, 4 blk/CU,
// 16 waves/CU). If dur returns to ~80, graph/ws structure is the knob; if it
// stays ~89, both configs sit on the same harness floor -> roofline.
// ---------------------------------------------------------------------------

typedef int v4i __attribute__((ext_vector_type(4)));
typedef unsigned int v4u __attribute__((ext_vector_type(4)));

// workspace layout (bytes)
#define WS_PART   0          // 144 floats: per-wave |w| max partials
#define WS_AQ     1024       // 4096*640 bytes: unfolded patch bytes [m][k], k=c*128+j

#define BROW  656   // LDS row stride bytes (164 dwords == 4 mod 32 banks -> free)
#define BROWD 164

// ---------------------------------------------------------------------------
// k_prep: im2col byte unfold (quantize floats on the fly) + weight max partials
// grid: 2560 unfold blocks + 36 weight blocks, 256 thr   (verbatim from R2)
// ---------------------------------------------------------------------------
__global__ __launch_bounds__(256) void k_prep(
    const float* __restrict__ in, const float* __restrict__ w,
    unsigned char* __restrict__ Aq, float* __restrict__ part,
    float* __restrict__ out_scalar)
{
  int bid = blockIdx.x, tid = threadIdx.x;
  if (bid == 0 && tid == 0) out_scalar[0] = 0.0f;   // second tuple output
  if (bid < 2560) {
    unsigned int widx = bid * 256 + tid;            // dword index: m*160 + kw
    unsigned int m  = ((widx >> 5) * 52429u) >> 18; // widx/160
    unsigned int kw = widx - m * 160;
    int b = m >> 10, p = m & 1023;
    int y = p >> 5, x = p & 31;
    unsigned int pack = 0;
    #pragma unroll
    for (int i = 0; i < 4; ++i) {
      unsigned int k = kw * 4 + i;
      unsigned int c = k >> 7;
      unsigned int j = k & 127;
      unsigned int csize = (c == 4) ? 112 : 116;
      unsigned int bv = 0;
      if (j < csize) {
        unsigned int f  = c * 116 + j;              // f = ic*9 + dy*3 + dx
        unsigned int ic = (f * 7282u) >> 16;        // f/9  (f<576)
        unsigned int r9 = f - ic * 9;
        unsigned int dy = (r9 * 11u) >> 5;          // r9/3
        unsigned int dx = r9 - dy * 3;
        int iy = y + (int)dy - 1, ix = x + (int)dx - 1;
        if (iy >= 0 && iy < 32 && ix >= 0 && ix < 32) {
          float xv = in[((b * 64 + (int)ic) * 32 + iy) * 32 + ix];
          xv = fminf(fmaxf(xv, -8.0f), 7.9375f);          // fixed-point clip
          bv = (unsigned int)((int)rintf(xv * 16.0f) & 255);  // 2's-compl byte
        }
      }
      pack |= bv << (8 * i);
    }
    ((unsigned int*)Aq)[widx] = pack;
  } else {
    int t = (bid - 2560) * 256 + tid;               // [0, 9216)
    const float4 wv = ((const float4*)w)[t];        // 4 consecutive weights
    float a = fmaxf(fmaxf(fabsf(wv.x), fabsf(wv.y)),
                    fmaxf(fabsf(wv.z), fabsf(wv.w)));
    #pragma unroll
    for (int off = 32; off > 0; off >>= 1)
      a = fmaxf(a, __shfl_down(a, off, 64));
    if ((tid & 63) == 0)
      part[(bid - 2560) * 4 + (tid >> 6)] = a;      // 144 partials
  }
}

// extract 2-bit field s of each byte in a packed dword vector
__device__ __forceinline__ v4i bits2(v4u w, int s) {
  v4u r = (w >> (unsigned)(2 * s)) & 0x03030303u;
  return (v4i)r;
}

// ---------------------------------------------------------------------------
// k_main: 16m x 16o per block, 4 waves = stream s 0..3; weights quantized into
// LDS per block; patches from L2-resident Aq; cross-s LDS reduce.
// grid: 1024 blocks (256 mtiles x 4 otiles) = 4 blk/CU, 16 waves/CU.
// ---------------------------------------------------------------------------
__global__ __launch_bounds__(256, 4) void k_main(
    const unsigned char* __restrict__ Aq, const float* __restrict__ w,
    const float* __restrict__ part, float* __restrict__ out)
{
  __shared__ __align__(16) unsigned char Bl[32 * BROW];  // [sign*16+o_l][kpos] 20992 B
  __shared__ __align__(16) v4i red[4 * 64];              // cross-s partials 4096 B
  __shared__ float s_norm;

  int tid = threadIdx.x;
  int bid = blockIdx.x;
  int mtile = bid >> 2;        // 16 consecutive patches
  int otile = bid & 3;         // o base = otile*16

  // ---- zero chunk-pad dwords of Bl (512 dwords) + norm reduce (wave 0) ----
  #pragma unroll
  for (int i = 0; i < 2; ++i) {
    int idx = i * 256 + tid;
    int row = idx >> 4, slot = idx & 15;
    int c, dw;
    if (slot < 12) { c = (slot * 11) >> 5; dw = 29 + slot - c * 3; }  // c<4: dw 29..31
    else           { c = 4;                dw = slot + 16; }          // c=4: dw 28..31
    ((unsigned int*)Bl)[row * BROWD + c * 32 + dw] = 0u;
  }
  if (tid < 64) {
    float a = part[tid];                                 // 144 partials
    a = fmaxf(a, part[tid + 64]);
    if (tid < 16) a = fmaxf(a, part[tid + 128]);
    #pragma unroll
    for (int off = 32; off > 0; off >>= 1)
      a = fmaxf(a, __shfl_down(a, off, 64));
    if (tid == 0) s_norm = (a > 0.0f) ? a : 1.0f;
  }
  __syncthreads();

  float norm = s_norm;
  float sc = 255.0f / norm;

  // ---- quantize this otile's 16o x 576f weights into Bl ----
  #pragma unroll 3
  for (int i = 0; i < 9; ++i) {
    int idx = i * 256 + tid;                              // [0,2304) float4 groups
    unsigned int o_l = ((unsigned)idx * 1821u) >> 18;     // idx/144
    int g = idx - (int)o_l * 144;
    int c, jg;
    if (g < 116) { c = (g * 565) >> 14; jg = (g - c * 29) * 4; }  // c=g/29
    else         { c = 4;               jg = (g - 116) * 4; }
    int f = c * 116 + jg;
    float4 wv = *(const float4*)(w + (otile * 16 + (int)o_l) * 576 + f);
    float vv[4] = {wv.x, wv.y, wv.z, wv.w};
    unsigned int pd = 0, nd = 0;
    #pragma unroll
    for (int q = 0; q < 4; ++q) {
      unsigned int pb = (unsigned int)(int)rintf(fmaxf(vv[q], 0.0f) * sc);
      unsigned int nb = (unsigned int)(int)rintf(fmaxf(-vv[q], 0.0f) * sc);
      pd |= pb << (8 * q);
      nd |= nb << (8 * q);
    }
    int dwo = c * 32 + (jg >> 2);
    ((unsigned int*)Bl)[(int)o_l * BROWD + dwo]        = pd;   // pos
    ((unsigned int*)Bl)[(16 + (int)o_l) * BROWD + dwo] = nd;   // neg
  }
  __syncthreads();

  // ---- MFMA: wave = stream s; weights = A-operand -> D[o][m] ----
  int lane = tid & 63, s = tid >> 6;
  int r16 = lane & 15, kgrp = lane >> 4;

  const unsigned char* ap = Aq + (mtile * 16 + r16) * 640 + kgrp * 16;  // patches (global/L2)
  const unsigned char* bp = Bl + r16 * BROW + kgrp * 16;                // pos weights (LDS)
  const unsigned char* bn = Bl + (16 + r16) * BROW + kgrp * 16;         // neg weights (LDS)

  v4i outacc = {0, 0, 0, 0};

  #pragma unroll
  for (int c = 0; c < 5; ++c) {
    v4u a0 = *(const v4u*)(ap + c * 128);
    v4u a1 = *(const v4u*)(ap + c * 128 + 64);
    v4u p0 = *(const v4u*)(bp + c * 128);
    v4u p1 = *(const v4u*)(bp + c * 128 + 64);
    v4u n0 = *(const v4u*)(bn + c * 128);
    v4u n1 = *(const v4u*)(bn + c * 128 + 64);

    v4i as0 = bits2(a0, s), as1 = bits2(a1, s);   // this wave's stream digits

    #pragma unroll
    for (int t = 0; t < 4; ++t) {
      v4i z = {0, 0, 0, 0};
      v4i pacc = __builtin_amdgcn_mfma_i32_16x16x64_i8(bits2(p0, t), as0, z, 0, 0, 0);
      pacc     = __builtin_amdgcn_mfma_i32_16x16x64_i8(bits2(p1, t), as1, pacc, 0, 0, 0);
      v4i nacc = __builtin_amdgcn_mfma_i32_16x16x64_i8(bits2(n0, t), as0, z, 0, 0, 0);
      nacc     = __builtin_amdgcn_mfma_i32_16x16x64_i8(bits2(n1, t), as1, nacc, 0, 0, 0);
      int sh = 2 * (s + t);
      #pragma unroll
      for (int r = 0; r < 4; ++r) {
        // ADC: nonneg int sums; clip(round(x),0,31) == min(x,31)
        int dd = (pacc[r] < 31 ? pacc[r] : 31) - (nacc[r] < 31 ? nacc[r] : 31);
        outacc[r] += dd << sh;    // per-s partial <= 843200, total <= 1.12e6, exact
      }
    }
  }

  // ---- cross-s reduce + store (wave s==0) ----
  red[s * 64 + lane] = outacc;
  __syncthreads();
  if (s == 0) {
    v4i acc = red[lane];
    #pragma unroll
    for (int ss = 1; ss < 4; ++ss)
      acc += red[ss * 64 + lane];
    float fsc = norm / 255.0f;
    int pg = mtile * 16 + r16;                   // global patch index
    int b = pg >> 10, p = pg & 1023;
    int oc = otile * 16 + kgrp * 4;
    #pragma unroll
    for (int r = 0; r < 4; ++r)                  // D: row(o)=kgrp*4+r, col(m)=r16
      out[(b * 64 + oc + r) * 1024 + p] = (float)acc[r] * fsc;
  }
}

extern "C" void kernel_launch(void* const* d_in, const int* in_sizes, int n_in,
                              void* d_out, int out_size, void* d_ws, size_t ws_size,
                              hipStream_t stream) {
  const float* inp = (const float*)d_in[0];   // (4,64,32,32) f32
  const float* wgt = (const float*)d_in[1];   // (64,64,3,3)  f32
  float* out = (float*)d_out;                 // 262144 + 1 f32
  unsigned char* ws = (unsigned char*)d_ws;

  float*         part = (float*)(ws + WS_PART);
  unsigned char* Aq   = ws + WS_AQ;

  k_prep<<<2596, 256, 0, stream>>>(inp, wgt, Aq, part, out + 262144);
  k_main<<<1024, 256, 0, stream>>>(Aq, wgt, part, out);
}